// Round 3
// baseline (346.070 us; speedup 1.0000x reference)
//
#include <hip/hip_runtime.h>
#include <hip/hip_bf16.h>

typedef float  float4v __attribute__((ext_vector_type(4)));
typedef short  short8v __attribute__((ext_vector_type(8)));
typedef short  short4v __attribute__((ext_vector_type(4)));
typedef __bf16 bf16x8  __attribute__((ext_vector_type(8)));
typedef float  f32x4   __attribute__((ext_vector_type(4)));

constexpr int NB = 512, T = 64, DIN = 1024, DOUT = 1024;

// ---- workspace layout (bf16-DMA path) ----
constexpr size_t ABF_BYTES = (size_t)NB * T * DIN * 2;   // 67,108,864
constexpr size_t WN_BYTES  = (size_t)DOUT * DIN * 2;     // 2,097,152
constexpr size_t WS_BF16   = ABF_BYTES + WN_BYTES;       // ~69 MB

__device__ __forceinline__ short f2bf_rne(float x) {
    return __builtin_bit_cast(short, __float2bfloat16(x));
}
__device__ __forceinline__ short f2bf_trunc(float x) {   // exact for {0,1}
    return (short)(__builtin_bit_cast(unsigned int, x) >> 16);
}
__device__ __forceinline__ void load_lds_16B(const void* g, void* l) {
    __builtin_amdgcn_global_load_lds(
        (const __attribute__((address_space(1))) unsigned int*)g,
        (__attribute__((address_space(3))) unsigned int*)l, 16, 0, 0);
}

// ---- fused prepass: A fp32{0,1} -> bf16 (trunc, exact) AND Wn = bf16(W*ratio)
constexpr int PREP_A_BLOCKS = NB * T * DIN / 8 / 256;    // 16384
constexpr int PREP_W_BLOCKS = DOUT * DIN / 4 / 256;      // 1024

__global__ void __launch_bounds__(256)
prep_fused(const float* __restrict__ A, short* __restrict__ Abf,
           const float* __restrict__ W, const float* __restrict__ gamma,
           const float* __restrict__ rvar, short* __restrict__ Wn) {
    const int b = blockIdx.x;
    if (b < PREP_A_BLOCKS) {
        int idx = b * 256 + threadIdx.x;                 // 8-elem group
        const float4v* p = (const float4v*)A + (size_t)idx * 2;
        float4v v0 = __builtin_nontemporal_load(p);
        float4v v1 = __builtin_nontemporal_load(p + 1);
        short8v s;
        #pragma unroll
        for (int j = 0; j < 4; j++) {
            s[j]     = f2bf_trunc(v0[j]);
            s[j + 4] = f2bf_trunc(v1[j]);
        }
        *((short8v*)Abf + idx) = s;                      // cached: re-read soon
    } else {
        int idx = (b - PREP_A_BLOCKS) * 256 + threadIdx.x;  // float4 group
        int o = idx >> 8;
        float r = gamma[o] / sqrtf(rvar[o]);
        float4v w = ((const float4v*)W)[idx];
        short4v s;
        #pragma unroll
        for (int j = 0; j < 4; j++) s[j] = f2bf_rne(w[j] * r);
        ((short4v*)Wn)[idx] = s;
    }
}

// standalone fold (used by the ws-small fallback path only)
__global__ void __launch_bounds__(256)
fold_w_kernel(const float* __restrict__ W, const float* __restrict__ gamma,
              const float* __restrict__ rvar, short* __restrict__ Wn) {
    int idx = blockIdx.x * 256 + threadIdx.x;
    int o = idx >> 8;
    float r = gamma[o] / sqrtf(rvar[o]);
    float4v w = ((const float4v*)W)[idx];
    short4v s;
    #pragma unroll
    for (int j = 0; j < 4; j++) s[j] = f2bf_rne(w[j] * r);
    ((short4v*)Wn)[idx] = s;
}

// =====================================================================
// main: 256x256 tile, BK=32, 1024 threads = 16 waves (4x4 grid),
// wave-tile 64x64 (acc=64 VGPR -> 4 waves/SIMD), triple-buffered LDS,
// one barrier per K-tile, counted vmcnt(2) (~1.3-tile staging lead).
//
// Pipeline (per thread, 2 global_load_lds per STAGE, FIFO vmcnt):
//   prologue: stage(0), stage(1) -> 4 in flight; vmcnt(2) retires tile 0.
//   tile t: stage(t+2) at top (2 loads); compute buf[t%3];
//           bottom vmcnt(2) retires tile t+1's loads (older than t+2's),
//           then s_barrier -> buf[(t+1)%3] ready for every wave.
//   WAR: stage(t+2) writes buf[(t+2)%3]=buf[(t-1)%3]; its readers (tile
//        t-1) all crossed the bottom-of-(t-1) barrier before this issues.
//   Overlap source: 4 waves/SIMD TLP (r0's proven mechanism), not
//   intra-wave phases (r1/r2 at 2 waves/SIMD stayed at 26% MfmaUtil).
// =====================================================================
constexpr int BM2 = 256, BN2 = 256, BK2 = 32;
constexpr int NT2  = DIN / BK2;                   // 32
constexpr int BUFB = (BM2 + BN2) * BK2 * 2;       // 32768 B per buffer
constexpr int BREG = BM2 * BK2 * 2;               // 16384: B region offset

__global__ void __launch_bounds__(1024, 4)
snn_gemm_if_256(const short* __restrict__ Abf,  // (N*T, DIN) bf16 {0,1}
                const short* __restrict__ Wn,   // (DOUT, DIN) bf16, BN-folded
                const float* __restrict__ bias, const float* __restrict__ gamma,
                const float* __restrict__ beta, const float* __restrict__ rmean,
                const float* __restrict__ rvar, float* __restrict__ out) {
    __shared__ __align__(16) char sm[3 * BUFB];   // 96 KB; potS aliases 64 KB
    __shared__ float bstepS[BN2];

    const int tid = threadIdx.x;
    // XCD-chunked swizzle: 512 blocks, 64 contiguous work items per XCD;
    // 4 consecutive works share one A panel -> same-XCD L2 reuse.
    const int work = (blockIdx.x & 7) * 64 + (blockIdx.x >> 3);
    const int oB = (work & 3) * BN2;
    const int rg = work >> 2;                     // A rows rg*256.., samples rg*4..

    if (tid < BN2) {
        int o = oB + tid;
        float r = gamma[o] / sqrtf(rvar[o]);
        bstepS[tid] = ((bias[o] - rmean[o]) * r + beta[o]) * (1.0f / 64.0f);
    }
    // retire bstep global loads so vmcnt accounting below is uniform
    asm volatile("s_waitcnt vmcnt(0)" ::: "memory");
    __builtin_amdgcn_sched_barrier(0);

    const int lane = tid & 63;
    const int wv   = tid >> 6;                    // 0..15
    const int wr   = wv >> 2;                     // 0..3: sample / M 64-row band
    const int wc   = wv & 3;                      // 0..3: N 64-col band
    const int l15  = lane & 15;
    const int quad = lane >> 4;

    // fragment ds_read byte offsets. BK=32 -> 4 chunks/row of 16 B.
    // swizzle: linear chunk c holds global chunk c ^ ((row>>1)&3) -> within
    // any 16-lane phase, rows map 2-way per bank group (free, m136).
    int aOff[4], bOff[4];
    #pragma unroll
    for (int i = 0; i < 4; i++) {
        int ra = wr * 64 + i * 16 + l15;
        int rb = wc * 64 + i * 16 + l15;
        aOff[i] = ra * 64 + ((quad ^ ((ra >> 1) & 3)) * 16);
        bOff[i] = BREG + rb * 64 + ((quad ^ ((rb >> 1) & 3)) * 16);
    }

    // staging: thread tid covers A slot tid and B slot tid of each buffer.
    // slot s: row=s>>2, linear chunk s&3 <- global chunk (s&3)^((row>>1)&3)
    // (inverse of the read swizzle; involution).
    const int srow = tid >> 2;
    const int gck  = (tid & 3) ^ ((srow >> 1) & 3);
    const short* gA = Abf + (size_t)(rg * BM2 + srow) * DIN + gck * 8;
    const short* gB = Wn + (size_t)(oB + srow) * DIN + gck * 8;
    const int dA = tid * 16;
    const int dB = BREG + tid * 16;

    auto STAGE = [&](int bufB) {                  // 2 loads; advances K by 32
        load_lds_16B(gA, sm + bufB + dA);
        load_lds_16B(gB, sm + bufB + dB);
        gA += BK2; gB += BK2;
    };
    auto LD8 = [&](const char* p) {
        return __builtin_bit_cast(bf16x8, *(const short8v*)p);
    };

    f32x4 acc[4][4] = {};

    // prologue: tiles 0,1 staged; tile 0 landed
    STAGE(0);
    STAGE(BUFB);
    asm volatile("s_waitcnt vmcnt(2)" ::: "memory");
    __builtin_amdgcn_sched_barrier(0);
    __builtin_amdgcn_s_barrier();
    __builtin_amdgcn_sched_barrier(0);

    int cb = 0, sb = 2 * BUFB;
    #pragma unroll 1
    for (int t = 0; t < NT2; ++t) {
        if (t < NT2 - 2) STAGE(sb);               // tile t+2
        const char* base = sm + cb;
        bf16x8 af[4], bv[4];
        #pragma unroll
        for (int i = 0; i < 4; i++) af[i] = LD8(base + aOff[i]);
        #pragma unroll
        for (int i = 0; i < 4; i++) bv[i] = LD8(base + bOff[i]);
        __builtin_amdgcn_s_setprio(1);
        #pragma unroll
        for (int mi = 0; mi < 4; mi++)
            #pragma unroll
            for (int ni = 0; ni < 4; ni++)
                acc[mi][ni] = __builtin_amdgcn_mfma_f32_16x16x32_bf16(
                    af[mi], bv[ni], acc[mi][ni], 0, 0, 0);
        __builtin_amdgcn_s_setprio(0);

        if (t < NT2 - 2) {
            asm volatile("s_waitcnt vmcnt(2)" ::: "memory"); // tile t+1 landed
        } else {
            asm volatile("s_waitcnt vmcnt(0)" ::: "memory");
        }
        __builtin_amdgcn_sched_barrier(0);
        __builtin_amdgcn_s_barrier();
        __builtin_amdgcn_sched_barrier(0);

        cb = (cb == 2 * BUFB) ? 0 : cb + BUFB;
        sb = (sb == 2 * BUFB) ? 0 : sb + BUFB;
    }

    // ---- epilogue: 4 rounds of 16 t-rows x 4 samples (64 KB alias) ----
    // pot[s][i][c] at s*16KB + i*1KB + (c ^ (((i>>2)&3)<<3))*4; all 16 waves
    // write each round (wave wr = sample), all 1024 threads scan.
    float* potS = (float*)sm;
    float pot = 0.f, cnt = 0.f;
    const int sc_s = tid >> 8;                    // 0..3: sample scanned
    const int sc_c = tid & 255;                   // column scanned
    const float bst = bstepS[sc_c];
    float* so = out + (size_t)(rg * 4 + sc_s) * T * DOUT + oB + sc_c;

    #pragma unroll 1
    for (int j = 0; j < 4; ++j) {                 // t-chunk = mi index
        #pragma unroll
        for (int ni = 0; ni < 4; ni++)
            #pragma unroll
            for (int r = 0; r < 4; r++) {
                int i   = quad * 4 + r;           // t-row within chunk
                int col = (wc * 64 + ni * 16 + l15) ^ (quad << 3);
                potS[wr * 4096 + i * 256 + col] = acc[j][ni][r];
            }
        __syncthreads();
        #pragma unroll
        for (int i = 0; i < 16; i++) {
            int t = j * 16 + i;
            pot += potS[sc_s * 4096 + i * 256 +
                        (sc_c ^ (((i >> 2) & 3) << 3))] + bst;
            float spk = (pot >= 1.0f) ? 1.0f : 0.0f;
            pot -= spk;
            cnt += spk;
            __builtin_nontemporal_store(spk, so + (size_t)t * DOUT);
        }
        __syncthreads();
    }
    __builtin_nontemporal_store(
        cnt, out + (size_t)NB * T * DOUT +
             (size_t)(rg * 4 + sc_s) * DOUT + oB + sc_c);
}

// ===================== fallback (round-2 proven path) =====================

constexpr int BM = 128, BN = 128, BK = 64;
constexpr int LDA_F = 72;
constexpr int A_BYTES_F = BM * LDA_F * 2;
constexpr int SMEM_F = A_BYTES_F + BN * BK * 2;

template <bool PREFOLD>
__global__ void __launch_bounds__(256)
snn_gemm_if(const float* __restrict__ A, const float* __restrict__ W,
            const short* __restrict__ Wn,
            const float* __restrict__ bias, const float* __restrict__ gamma,
            const float* __restrict__ beta, const float* __restrict__ rmean,
            const float* __restrict__ rvar, float* __restrict__ out) {
    __shared__ __align__(16) char smem[SMEM_F];
    __shared__ float ratioS[BN];
    __shared__ float bstepS[BN];
    short* AsS  = (short*)smem;
    short* BsS  = (short*)(smem + A_BYTES_F);
    float* potS = (float*)smem;

    const int tid   = threadIdx.x;
    const int by    = blockIdx.y;
    const int oBase = blockIdx.x * BN;

    if (tid < BN) {
        int o = oBase + tid;
        float r = gamma[o] / sqrtf(rvar[o]);
        ratioS[tid] = r;
        bstepS[tid] = ((bias[o] - rmean[o]) * r + beta[o]) * (1.0f / 64.0f);
    }
    __syncthreads();

    const int lane = tid & 63;
    const int wv   = tid >> 6;
    const int wr   = wv & 1;
    const int wc   = wv >> 1;
    const int l15  = lane & 15;
    const int quad = lane >> 4;

    f32x4 acc[4][4] = {};
    const float* Ab = A + (size_t)by * BM * DIN;

    for (int kb = 0; kb < DIN; kb += BK) {
        float4v av[4][2];
        #pragma unroll
        for (int i = 0; i < 4; i++) {
            int g = i * 256 + tid;
            int r = g >> 3, k8 = g & 7;
            const float4v* p = (const float4v*)(Ab + (size_t)r * DIN + kb + k8 * 8);
            av[i][0] = p[0];
            av[i][1] = p[1];
        }
        float4v bv[4][2];
        if constexpr (!PREFOLD) {
            #pragma unroll
            for (int i = 0; i < 4; i++) {
                int slot = i * 256 + tid;
                int r = slot >> 3, k8 = (slot & 7) ^ (r & 7);
                const float4v* p = (const float4v*)(W + (size_t)(oBase + r) * DIN + kb + k8 * 8);
                bv[i][0] = p[0];
                bv[i][1] = p[1];
            }
        }
        __syncthreads();

        if constexpr (PREFOLD) {
            #pragma unroll
            for (int i = 0; i < 4; i++) {
                int slot = i * 256 + tid;
                int r = slot >> 3, k8 = (slot & 7) ^ (r & 7);
                load_lds_16B(Wn + (size_t)(oBase + r) * DIN + kb + k8 * 8,
                             BsS + (size_t)slot * 8);
            }
        } else {
            #pragma unroll
            for (int i = 0; i < 4; i++) {
                int slot = i * 256 + tid;
                int r = slot >> 3;
                float rt = ratioS[r];
                short8v s;
                #pragma unroll
                for (int j = 0; j < 4; j++) {
                    s[j]     = f2bf_rne(bv[i][0][j] * rt);
                    s[j + 4] = f2bf_rne(bv[i][1][j] * rt);
                }
                *(short8v*)(BsS + (size_t)slot * 8) = s;
            }
        }
        #pragma unroll
        for (int i = 0; i < 4; i++) {
            int g = i * 256 + tid;
            int r = g >> 3, k8 = g & 7;
            short8v s;
            #pragma unroll
            for (int j = 0; j < 4; j++) {
                s[j]     = f2bf_trunc(av[i][0][j]);
                s[j + 4] = f2bf_trunc(av[i][1][j]);
            }
            *(short8v*)(&AsS[r * LDA_F + k8 * 8]) = s;
        }
        __syncthreads();

        #pragma unroll
        for (int ks = 0; ks < 2; ks++) {
            bf16x8 af[4], bfv[4];
            #pragma unroll
            for (int mi = 0; mi < 4; mi++)
                af[mi] = __builtin_bit_cast(bf16x8,
                    *(const short8v*)(&AsS[(wr * 64 + mi * 16 + l15) * LDA_F + ks * 32 + quad * 8]));
            #pragma unroll
            for (int ni = 0; ni < 4; ni++) {
                int row  = wc * 64 + ni * 16 + l15;
                int slot = row * 8 + ((ks * 4 + quad) ^ (l15 & 7));
                bfv[ni] = __builtin_bit_cast(bf16x8, *(const short8v*)(BsS + (size_t)slot * 8));
            }
            #pragma unroll
            for (int mi = 0; mi < 4; mi++)
                #pragma unroll
                for (int ni = 0; ni < 4; ni++)
                    acc[mi][ni] = __builtin_amdgcn_mfma_f32_16x16x32_bf16(
                        af[mi], bfv[ni], acc[mi][ni], 0, 0, 0);
        }
    }

    __syncthreads();

    #pragma unroll 1
    for (int s = 0; s < 2; s++) {
        if (wr == s) {
            #pragma unroll
            for (int mi = 0; mi < 4; mi++)
                #pragma unroll
                for (int ni = 0; ni < 4; ni++)
                    #pragma unroll
                    for (int r = 0; r < 4; r++)
                        potS[(mi * 16 + quad * 4 + r) * BN + wc * 64 + ni * 16 + l15] =
                            acc[mi][ni][r];
        }
        __syncthreads();
        if (tid < BN) {
            int n = by * 2 + s;
            float pot = 0.f, cnt = 0.f;
            const float bst = bstepS[tid];
            float* so = out + (size_t)n * T * DOUT + oBase + tid;
            for (int t = 0; t < T; t++) {
                pot += potS[t * BN + tid] + bst;
                float spk = (pot >= 1.0f) ? 1.0f : 0.0f;
                pot -= spk;
                cnt += spk;
                so[(size_t)t * DOUT] = spk;
            }
            out[(size_t)NB * T * DOUT + (size_t)n * DOUT + oBase + tid] = cnt;
        }
        __syncthreads();
    }
}

extern "C" void kernel_launch(void* const* d_in, const int* in_sizes, int n_in,
                              void* d_out, int out_size, void* d_ws, size_t ws_size,
                              hipStream_t stream) {
    const float* A     = (const float*)d_in[0];
    // d_in[1] (input_features_sc) feeds only the un-returned ANN path — dead.
    const float* W     = (const float*)d_in[2];
    const float* bias  = (const float*)d_in[3];
    const float* gamma = (const float*)d_in[4];
    const float* beta  = (const float*)d_in[5];
    const float* rmean = (const float*)d_in[6];
    const float* rvar  = (const float*)d_in[7];
    float* out = (float*)d_out;

    if (d_ws != nullptr && ws_size >= WS_BF16) {
        short* Abf = (short*)d_ws;
        short* Wn  = (short*)((char*)d_ws + ABF_BYTES);
        prep_fused<<<PREP_A_BLOCKS + PREP_W_BLOCKS, 256, 0, stream>>>(
            A, Abf, W, gamma, rvar, Wn);
        snn_gemm_if_256<<<dim3(512), 1024, 0, stream>>>(Abf, Wn, bias, gamma, beta,
                                                        rmean, rvar, out);
    } else if (d_ws != nullptr && ws_size >= WN_BYTES) {
        short* Wn = (short*)d_ws;
        fold_w_kernel<<<DOUT * DIN / 4 / 256, 256, 0, stream>>>(W, gamma, rvar, Wn);
        dim3 grid(DOUT / BN, NB / 2);
        snn_gemm_if<true><<<grid, 256, 0, stream>>>(A, W, Wn, bias, gamma, beta,
                                                    rmean, rvar, out);
    } else {
        dim3 grid(DOUT / BN, NB / 2);
        snn_gemm_if<false><<<grid, 256, 0, stream>>>(A, W, nullptr, bias, gamma, beta,
                                                     rmean, rvar, out);
    }
}

// Round 4
// 307.024 us; speedup vs baseline: 1.1272x; 1.1272x over previous
//
#include <hip/hip_runtime.h>
#include <hip/hip_bf16.h>

typedef float  float4v __attribute__((ext_vector_type(4)));
typedef short  short8v __attribute__((ext_vector_type(8)));
typedef short  short4v __attribute__((ext_vector_type(4)));
typedef __bf16 bf16x8  __attribute__((ext_vector_type(8)));
typedef float  f32x4   __attribute__((ext_vector_type(4)));

constexpr int NB = 512, T = 64, DIN = 1024, DOUT = 1024;

// ---- workspace layout (bf16-DMA path) ----
constexpr size_t ABF_BYTES = (size_t)NB * T * DIN * 2;   // 67,108,864
constexpr size_t WN_BYTES  = (size_t)DOUT * DIN * 2;     // 2,097,152
constexpr size_t WS_BF16   = ABF_BYTES + WN_BYTES;       // ~69 MB

__device__ __forceinline__ short f2bf_rne(float x) {
    return __builtin_bit_cast(short, __float2bfloat16(x));
}
__device__ __forceinline__ short f2bf_trunc(float x) {   // exact for {0,1}
    return (short)(__builtin_bit_cast(unsigned int, x) >> 16);
}
__device__ __forceinline__ void load_lds_16B(const void* g, void* l) {
    __builtin_amdgcn_global_load_lds(
        (const __attribute__((address_space(1))) unsigned int*)g,
        (__attribute__((address_space(3))) unsigned int*)l, 16, 0, 0);
}

// ---- fused prepass: A fp32{0,1} -> bf16 (trunc, exact) AND Wn = bf16(W*ratio)
constexpr int PREP_A_BLOCKS = NB * T * DIN / 8 / 256;    // 16384
constexpr int PREP_W_BLOCKS = DOUT * DIN / 4 / 256;      // 1024

__global__ void __launch_bounds__(256)
prep_fused(const float* __restrict__ A, short* __restrict__ Abf,
           const float* __restrict__ W, const float* __restrict__ gamma,
           const float* __restrict__ rvar, short* __restrict__ Wn) {
    const int b = blockIdx.x;
    if (b < PREP_A_BLOCKS) {
        int idx = b * 256 + threadIdx.x;                 // 8-elem group
        const float4v* p = (const float4v*)A + (size_t)idx * 2;
        float4v v0 = __builtin_nontemporal_load(p);
        float4v v1 = __builtin_nontemporal_load(p + 1);
        short8v s;
        #pragma unroll
        for (int j = 0; j < 4; j++) {
            s[j]     = f2bf_trunc(v0[j]);
            s[j + 4] = f2bf_trunc(v1[j]);
        }
        *((short8v*)Abf + idx) = s;                      // cached: re-read soon
    } else {
        int idx = (b - PREP_A_BLOCKS) * 256 + threadIdx.x;  // float4 group
        int o = idx >> 8;
        float r = gamma[o] / sqrtf(rvar[o]);
        float4v w = ((const float4v*)W)[idx];
        short4v s;
        #pragma unroll
        for (int j = 0; j < 4; j++) s[j] = f2bf_rne(w[j] * r);
        ((short4v*)Wn)[idx] = s;
    }
}

// standalone fold (used by the ws-small fallback path only)
__global__ void __launch_bounds__(256)
fold_w_kernel(const float* __restrict__ W, const float* __restrict__ gamma,
              const float* __restrict__ rvar, short* __restrict__ Wn) {
    int idx = blockIdx.x * 256 + threadIdx.x;
    int o = idx >> 8;
    float r = gamma[o] / sqrtf(rvar[o]);
    float4v w = ((const float4v*)W)[idx];
    short4v s;
    #pragma unroll
    for (int j = 0; j < 4; j++) s[j] = f2bf_rne(w[j] * r);
    ((short4v*)Wn)[idx] = s;
}

// =====================================================================
// main: 256x256 tile, BK=32, 1024 threads = 16 waves (4x4 grid),
// wave-tile 64x64 (acc=64 VGPR -> 4 waves/SIMD), triple-buffered LDS,
// one barrier per K-tile, counted vmcnt(2) (~1.3-tile staging lead).
//
// r4 fix over r3: epilogue j-loop FULLY unrolled so every acc[j][ni][r]
// index is compile-time-constant. r3's `#pragma unroll 1` made j a
// runtime index -> whole acc array spilled to scratch (rule #20):
// VGPR_Count dropped to 60, WRITE_SIZE 133->264 MB, FETCH 49->113 MB.
// =====================================================================
constexpr int BM2 = 256, BN2 = 256, BK2 = 32;
constexpr int NT2  = DIN / BK2;                   // 32
constexpr int BUFB = (BM2 + BN2) * BK2 * 2;       // 32768 B per buffer
constexpr int BREG = BM2 * BK2 * 2;               // 16384: B region offset

__global__ void __launch_bounds__(1024, 4)
snn_gemm_if_256(const short* __restrict__ Abf,  // (N*T, DIN) bf16 {0,1}
                const short* __restrict__ Wn,   // (DOUT, DIN) bf16, BN-folded
                const float* __restrict__ bias, const float* __restrict__ gamma,
                const float* __restrict__ beta, const float* __restrict__ rmean,
                const float* __restrict__ rvar, float* __restrict__ out) {
    __shared__ __align__(16) char sm[3 * BUFB];   // 96 KB; potS aliases 64 KB
    __shared__ float bstepS[BN2];

    const int tid = threadIdx.x;
    // XCD-chunked swizzle: 512 blocks, 64 contiguous work items per XCD;
    // 4 consecutive works share one A panel -> same-XCD L2 reuse.
    const int work = (blockIdx.x & 7) * 64 + (blockIdx.x >> 3);
    const int oB = (work & 3) * BN2;
    const int rg = work >> 2;                     // A rows rg*256.., samples rg*4..

    if (tid < BN2) {
        int o = oB + tid;
        float r = gamma[o] / sqrtf(rvar[o]);
        bstepS[tid] = ((bias[o] - rmean[o]) * r + beta[o]) * (1.0f / 64.0f);
    }
    // retire bstep global loads so vmcnt accounting below is uniform
    asm volatile("s_waitcnt vmcnt(0)" ::: "memory");
    __builtin_amdgcn_sched_barrier(0);

    const int lane = tid & 63;
    const int wv   = tid >> 6;                    // 0..15
    const int wr   = wv >> 2;                     // 0..3: sample / M 64-row band
    const int wc   = wv & 3;                      // 0..3: N 64-col band
    const int l15  = lane & 15;
    const int quad = lane >> 4;

    // fragment ds_read byte offsets. BK=32 -> 4 chunks/row of 16 B.
    // swizzle: linear chunk c holds global chunk c ^ ((row>>1)&3) -> within
    // any 16-lane phase, rows map 2-way per bank group (free, m136).
    int aOff[4], bOff[4];
    #pragma unroll
    for (int i = 0; i < 4; i++) {
        int ra = wr * 64 + i * 16 + l15;
        int rb = wc * 64 + i * 16 + l15;
        aOff[i] = ra * 64 + ((quad ^ ((ra >> 1) & 3)) * 16);
        bOff[i] = BREG + rb * 64 + ((quad ^ ((rb >> 1) & 3)) * 16);
    }

    // staging: thread tid covers A slot tid and B slot tid of each buffer.
    // slot s: row=s>>2, linear chunk s&3 <- global chunk (s&3)^((row>>1)&3)
    // (inverse of the read swizzle; involution).
    const int srow = tid >> 2;
    const int gck  = (tid & 3) ^ ((srow >> 1) & 3);
    const short* gA = Abf + (size_t)(rg * BM2 + srow) * DIN + gck * 8;
    const short* gB = Wn + (size_t)(oB + srow) * DIN + gck * 8;
    const int dA = tid * 16;
    const int dB = BREG + tid * 16;

    auto STAGE = [&](int bufB) {                  // 2 loads; advances K by 32
        load_lds_16B(gA, sm + bufB + dA);
        load_lds_16B(gB, sm + bufB + dB);
        gA += BK2; gB += BK2;
    };
    auto LD8 = [&](const char* p) {
        return __builtin_bit_cast(bf16x8, *(const short8v*)p);
    };

    f32x4 acc[4][4] = {};

    // prologue: tiles 0,1 staged; tile 0 landed
    STAGE(0);
    STAGE(BUFB);
    asm volatile("s_waitcnt vmcnt(2)" ::: "memory");
    __builtin_amdgcn_sched_barrier(0);
    __builtin_amdgcn_s_barrier();
    __builtin_amdgcn_sched_barrier(0);

    int cb = 0, sb = 2 * BUFB;
    #pragma unroll 1
    for (int t = 0; t < NT2; ++t) {
        if (t < NT2 - 2) STAGE(sb);               // tile t+2
        const char* base = sm + cb;
        bf16x8 af[4], bv[4];
        #pragma unroll
        for (int i = 0; i < 4; i++) af[i] = LD8(base + aOff[i]);
        #pragma unroll
        for (int i = 0; i < 4; i++) bv[i] = LD8(base + bOff[i]);
        __builtin_amdgcn_s_setprio(1);
        #pragma unroll
        for (int mi = 0; mi < 4; mi++)
            #pragma unroll
            for (int ni = 0; ni < 4; ni++)
                acc[mi][ni] = __builtin_amdgcn_mfma_f32_16x16x32_bf16(
                    af[mi], bv[ni], acc[mi][ni], 0, 0, 0);
        __builtin_amdgcn_s_setprio(0);

        if (t < NT2 - 2) {
            asm volatile("s_waitcnt vmcnt(2)" ::: "memory"); // tile t+1 landed
        } else {
            asm volatile("s_waitcnt vmcnt(0)" ::: "memory");
        }
        __builtin_amdgcn_sched_barrier(0);
        __builtin_amdgcn_s_barrier();
        __builtin_amdgcn_sched_barrier(0);

        cb = (cb == 2 * BUFB) ? 0 : cb + BUFB;
        sb = (sb == 2 * BUFB) ? 0 : sb + BUFB;
    }

    // ---- epilogue: 4 rounds of 16 t-rows x 4 samples (64 KB alias) ----
    // pot[s][i][c] at s*16KB + i*1KB + (c ^ (((i>>2)&3)<<3))*4; all 16 waves
    // write each round (wave wr = sample), all 1024 threads scan.
    // FULLY UNROLLED over j: acc indices must be compile-time (rule #20).
    float* potS = (float*)sm;
    float pot = 0.f, cnt = 0.f;
    const int sc_s = tid >> 8;                    // 0..3: sample scanned
    const int sc_c = tid & 255;                   // column scanned
    const float bst = bstepS[sc_c];
    float* so = out + (size_t)(rg * 4 + sc_s) * T * DOUT + oB + sc_c;

    #pragma unroll
    for (int j = 0; j < 4; ++j) {                 // t-chunk = mi index
        #pragma unroll
        for (int ni = 0; ni < 4; ni++)
            #pragma unroll
            for (int r = 0; r < 4; r++) {
                int i   = quad * 4 + r;           // t-row within chunk
                int col = (wc * 64 + ni * 16 + l15) ^ (quad << 3);
                potS[wr * 4096 + i * 256 + col] = acc[j][ni][r];
            }
        __syncthreads();
        #pragma unroll
        for (int i = 0; i < 16; i++) {
            int t = j * 16 + i;
            pot += potS[sc_s * 4096 + i * 256 +
                        (sc_c ^ (((i >> 2) & 3) << 3))] + bst;
            float spk = (pot >= 1.0f) ? 1.0f : 0.0f;
            pot -= spk;
            cnt += spk;
            __builtin_nontemporal_store(spk, so + (size_t)t * DOUT);
        }
        __syncthreads();
    }
    __builtin_nontemporal_store(
        cnt, out + (size_t)NB * T * DOUT +
             (size_t)(rg * 4 + sc_s) * DOUT + oB + sc_c);
}

// ===================== fallback (round-2 proven path) =====================

constexpr int BM = 128, BN = 128, BK = 64;
constexpr int LDA_F = 72;
constexpr int A_BYTES_F = BM * LDA_F * 2;
constexpr int SMEM_F = A_BYTES_F + BN * BK * 2;

template <bool PREFOLD>
__global__ void __launch_bounds__(256)
snn_gemm_if(const float* __restrict__ A, const float* __restrict__ W,
            const short* __restrict__ Wn,
            const float* __restrict__ bias, const float* __restrict__ gamma,
            const float* __restrict__ beta, const float* __restrict__ rmean,
            const float* __restrict__ rvar, float* __restrict__ out) {
    __shared__ __align__(16) char smem[SMEM_F];
    __shared__ float ratioS[BN];
    __shared__ float bstepS[BN];
    short* AsS  = (short*)smem;
    short* BsS  = (short*)(smem + A_BYTES_F);
    float* potS = (float*)smem;

    const int tid   = threadIdx.x;
    const int by    = blockIdx.y;
    const int oBase = blockIdx.x * BN;

    if (tid < BN) {
        int o = oBase + tid;
        float r = gamma[o] / sqrtf(rvar[o]);
        ratioS[tid] = r;
        bstepS[tid] = ((bias[o] - rmean[o]) * r + beta[o]) * (1.0f / 64.0f);
    }
    __syncthreads();

    const int lane = tid & 63;
    const int wv   = tid >> 6;
    const int wr   = wv & 1;
    const int wc   = wv >> 1;
    const int l15  = lane & 15;
    const int quad = lane >> 4;

    f32x4 acc[4][4] = {};
    const float* Ab = A + (size_t)by * BM * DIN;

    for (int kb = 0; kb < DIN; kb += BK) {
        float4v av[4][2];
        #pragma unroll
        for (int i = 0; i < 4; i++) {
            int g = i * 256 + tid;
            int r = g >> 3, k8 = g & 7;
            const float4v* p = (const float4v*)(Ab + (size_t)r * DIN + kb + k8 * 8);
            av[i][0] = p[0];
            av[i][1] = p[1];
        }
        float4v bv[4][2];
        if constexpr (!PREFOLD) {
            #pragma unroll
            for (int i = 0; i < 4; i++) {
                int slot = i * 256 + tid;
                int r = slot >> 3, k8 = (slot & 7) ^ (r & 7);
                const float4v* p = (const float4v*)(W + (size_t)(oBase + r) * DIN + kb + k8 * 8);
                bv[i][0] = p[0];
                bv[i][1] = p[1];
            }
        }
        __syncthreads();

        if constexpr (PREFOLD) {
            #pragma unroll
            for (int i = 0; i < 4; i++) {
                int slot = i * 256 + tid;
                int r = slot >> 3, k8 = (slot & 7) ^ (r & 7);
                load_lds_16B(Wn + (size_t)(oBase + r) * DIN + kb + k8 * 8,
                             BsS + (size_t)slot * 8);
            }
        } else {
            #pragma unroll
            for (int i = 0; i < 4; i++) {
                int slot = i * 256 + tid;
                int r = slot >> 3;
                float rt = ratioS[r];
                short8v s;
                #pragma unroll
                for (int j = 0; j < 4; j++) {
                    s[j]     = f2bf_rne(bv[i][0][j] * rt);
                    s[j + 4] = f2bf_rne(bv[i][1][j] * rt);
                }
                *(short8v*)(BsS + (size_t)slot * 8) = s;
            }
        }
        #pragma unroll
        for (int i = 0; i < 4; i++) {
            int g = i * 256 + tid;
            int r = g >> 3, k8 = g & 7;
            short8v s;
            #pragma unroll
            for (int j = 0; j < 4; j++) {
                s[j]     = f2bf_trunc(av[i][0][j]);
                s[j + 4] = f2bf_trunc(av[i][1][j]);
            }
            *(short8v*)(&AsS[r * LDA_F + k8 * 8]) = s;
        }
        __syncthreads();

        #pragma unroll
        for (int ks = 0; ks < 2; ks++) {
            bf16x8 af[4], bfv[4];
            #pragma unroll
            for (int mi = 0; mi < 4; mi++)
                af[mi] = __builtin_bit_cast(bf16x8,
                    *(const short8v*)(&AsS[(wr * 64 + mi * 16 + l15) * LDA_F + ks * 32 + quad * 8]));
            #pragma unroll
            for (int ni = 0; ni < 4; ni++) {
                int row  = wc * 64 + ni * 16 + l15;
                int slot = row * 8 + ((ks * 4 + quad) ^ (l15 & 7));
                bfv[ni] = __builtin_bit_cast(bf16x8, *(const short8v*)(BsS + (size_t)slot * 8));
            }
            #pragma unroll
            for (int mi = 0; mi < 4; mi++)
                #pragma unroll
                for (int ni = 0; ni < 4; ni++)
                    acc[mi][ni] = __builtin_amdgcn_mfma_f32_16x16x32_bf16(
                        af[mi], bfv[ni], acc[mi][ni], 0, 0, 0);
        }
    }

    __syncthreads();

    #pragma unroll 1
    for (int s = 0; s < 2; s++) {
        if (wr == s) {
            #pragma unroll
            for (int mi = 0; mi < 4; mi++)
                #pragma unroll
                for (int ni = 0; ni < 4; ni++)
                    #pragma unroll
                    for (int r = 0; r < 4; r++)
                        potS[(mi * 16 + quad * 4 + r) * BN + wc * 64 + ni * 16 + l15] =
                            acc[mi][ni][r];
        }
        __syncthreads();
        if (tid < BN) {
            int n = by * 2 + s;
            float pot = 0.f, cnt = 0.f;
            const float bst = bstepS[tid];
            float* so = out + (size_t)n * T * DOUT + oBase + tid;
            for (int t = 0; t < T; t++) {
                pot += potS[t * BN + tid] + bst;
                float spk = (pot >= 1.0f) ? 1.0f : 0.0f;
                pot -= spk;
                cnt += spk;
                so[(size_t)t * DOUT] = spk;
            }
            out[(size_t)NB * T * DOUT + (size_t)n * DOUT + oBase + tid] = cnt;
        }
        __syncthreads();
    }
}

extern "C" void kernel_launch(void* const* d_in, const int* in_sizes, int n_in,
                              void* d_out, int out_size, void* d_ws, size_t ws_size,
                              hipStream_t stream) {
    const float* A     = (const float*)d_in[0];
    // d_in[1] (input_features_sc) feeds only the un-returned ANN path — dead.
    const float* W     = (const float*)d_in[2];
    const float* bias  = (const float*)d_in[3];
    const float* gamma = (const float*)d_in[4];
    const float* beta  = (const float*)d_in[5];
    const float* rmean = (const float*)d_in[6];
    const float* rvar  = (const float*)d_in[7];
    float* out = (float*)d_out;

    if (d_ws != nullptr && ws_size >= WS_BF16) {
        short* Abf = (short*)d_ws;
        short* Wn  = (short*)((char*)d_ws + ABF_BYTES);
        prep_fused<<<PREP_A_BLOCKS + PREP_W_BLOCKS, 256, 0, stream>>>(
            A, Abf, W, gamma, rvar, Wn);
        snn_gemm_if_256<<<dim3(512), 1024, 0, stream>>>(Abf, Wn, bias, gamma, beta,
                                                        rmean, rvar, out);
    } else if (d_ws != nullptr && ws_size >= WN_BYTES) {
        short* Wn = (short*)d_ws;
        fold_w_kernel<<<DOUT * DIN / 4 / 256, 256, 0, stream>>>(W, gamma, rvar, Wn);
        dim3 grid(DOUT / BN, NB / 2);
        snn_gemm_if<true><<<grid, 256, 0, stream>>>(A, W, Wn, bias, gamma, beta,
                                                    rmean, rvar, out);
    } else {
        dim3 grid(DOUT / BN, NB / 2);
        snn_gemm_if<false><<<grid, 256, 0, stream>>>(A, W, nullptr, bias, gamma, beta,
                                                     rmean, rvar, out);
    }
}